// Round 4
// baseline (142.042 us; speedup 1.0000x reference)
//
#include <hip/hip_runtime.h>
#include <hip/hip_cooperative_groups.h>

namespace cg = cooperative_groups;

// BPR-style pairwise ranking loss.
// loss = -sum_b sum_{i<j} log_sigmoid((p_i-p_j)(t_i-t_j)) * (t_i-t_j)^2 * m_i*m_j
// With t in {0,1}: only (valid-pos, valid-neg) pairs contribute, each unordered
// pair exactly once, with term log_sigmoid(p_pos - p_neg). So per row:
//   loss_b = -sum_{i in P} sum_{j in N} log_sigmoid(p_i - p_j)
// Base-2 form: log_sigmoid(x) = ln2 * (min(y,0) - log2(1 + 2^-|y|)), y = x*log2e.
//
// Single COOPERATIVE kernel: block b computes partial[b], grid.sync(), then
// block 0 reduces all partials in fixed order (bit-deterministic) and writes
// out[0]. No counter, no memset node (R3 showed an in-graph 4B memset costs
// ~40 us). Agent-scope atomics for partial[] visibility across the 8
// non-coherent per-XCD L2s. 1024 blocks x 256 thr = 4 blocks/CU resident
// (16 VGPR, 3.5KB LDS -> >=8 blocks/CU capacity), cooperative-legal.

#define BATCH 1024
#define LEN   256
#define LN2f   0.6931471805599453f
#define LOG2Ef 1.4426950408889634f

__global__ __launch_bounds__(256) void bpr_coop_kernel(
    const float* __restrict__ preds,
    const int*   __restrict__ targets,
    const int*   __restrict__ mask,
    float*       __restrict__ partial,   // BATCH floats in ws
    float*       __restrict__ out)
{
    __shared__ float spos[LEN];     // positives' preds * log2e (compacted)
    __shared__ float sneg[LEN];     // negatives' preds * log2e (compacted)
    __shared__ int   wcp[4], wcn[4];
    __shared__ float wpart[4];

    const int b    = blockIdx.x;
    const int tid  = threadIdx.x;
    const int wid  = tid >> 6;
    const int lane = tid & 63;

    const float p = preds[b * LEN + tid] * LOG2Ef;
    const int   t = targets[b * LEN + tid];
    const int   m = mask[b * LEN + tid];

    const bool ispos = (m != 0) && (t != 0);
    const bool isneg = (m != 0) && (t == 0);

    const unsigned long long bp = __ballot(ispos);
    const unsigned long long bn = __ballot(isneg);
    if (lane == 0) { wcp[wid] = __popcll(bp); wcn[wid] = __popcll(bn); }
    __syncthreads();

    int opos = 0, oneg = 0;
    for (int w = 0; w < wid; ++w) { opos += wcp[w]; oneg += wcn[w]; }
    const int np = wcp[0] + wcp[1] + wcp[2] + wcp[3];
    const int nn = wcn[0] + wcn[1] + wcn[2] + wcn[3];

    const unsigned long long below = (1ull << lane) - 1ull;
    if (ispos) spos[opos + __popcll(bp & below)] = p;
    if (isneg) sneg[oneg + __popcll(bn & below)] = p;
    __syncthreads();

    // Waves split the negative range (j uniform per wave -> LDS broadcast);
    // lanes stride the positives.
    float acc = 0.0f;
    for (int i = lane; i < np; i += 64) {
        const float yi = spos[i];
        for (int j = wid; j < nn; j += 4) {
            const float y = yi - sneg[j];
            const float e = __builtin_amdgcn_exp2f(-fabsf(y)); // v_exp_f32 -abs
            const float l = __builtin_amdgcn_logf(1.0f + e);   // v_log_f32 (log2)
            acc += fminf(y, 0.0f) - l;
        }
    }

    for (int off = 32; off > 0; off >>= 1)
        acc += __shfl_down(acc, off, 64);
    if (lane == 0) wpart[wid] = acc;
    __syncthreads();

    if (tid == 0) {
        const float bsum = wpart[0] + wpart[1] + wpart[2] + wpart[3];
        __hip_atomic_store(&partial[b], bsum, __ATOMIC_RELEASE,
                           __HIP_MEMORY_SCOPE_AGENT);
    }

    cg::this_grid().sync();

    if (b == 0) {
        float racc = 0.0f;
        #pragma unroll
        for (int k = tid; k < BATCH; k += 256)
            racc += __hip_atomic_load(&partial[k], __ATOMIC_ACQUIRE,
                                      __HIP_MEMORY_SCOPE_AGENT);

        for (int off = 32; off > 0; off >>= 1)
            racc += __shfl_down(racc, off, 64);
        if (lane == 0) wpart[wid] = racc;
        __syncthreads();
        if (tid == 0)
            out[0] = -LN2f * (wpart[0] + wpart[1] + wpart[2] + wpart[3]);
    }
}

extern "C" void kernel_launch(void* const* d_in, const int* in_sizes, int n_in,
                              void* d_out, int out_size, void* d_ws, size_t ws_size,
                              hipStream_t stream) {
    const float* preds   = (const float*)d_in[0];
    const int*   targets = (const int*)d_in[1];
    const int*   mask    = (const int*)d_in[2];
    float* out     = (float*)d_out;
    float* partial = (float*)d_ws;   // BATCH floats of scratch

    void* args[] = { (void*)&preds, (void*)&targets, (void*)&mask,
                     (void*)&partial, (void*)&out };
    hipLaunchCooperativeKernel((const void*)bpr_coop_kernel,
                               dim3(BATCH), dim3(256), args, 0, stream);
}

// Round 5
// 41.574 us; speedup vs baseline: 3.4166x; 3.4166x over previous
//
#include <hip/hip_runtime.h>

// BPR-style pairwise ranking loss.
// loss = -sum_b sum_{i<j} log_sigmoid((p_i-p_j)(t_i-t_j)) * (t_i-t_j)^2 * m_i*m_j
// With t in {0,1}: only (valid-pos, valid-neg) pairs contribute, each unordered
// pair exactly once, with term log_sigmoid(p_pos - p_neg). So per row:
//   loss_b = -sum_{i in P} sum_{j in N} log_sigmoid(p_i - p_j)
// Base-2 form: log_sigmoid(x) = ln2 * (min(y,0) - log2(1 + 2^-|y|)), y = x*log2e.
//
// Two custom kernel nodes (R1 showed custom-node transitions cost ~0.2 us;
// R3 showed a 4-byte MEMSET node costs ~40 us -- never use memset nodes):
//   1. zero_counter_kernel: 1 thread, resets the arrival counter each call.
//   2. bpr_fused_kernel: block b computes partial[b]; last block (agent-scope
//      ticket counter) reduces all partials in fixed order -> out[0].
// Bit-deterministic: counter add order doesn't affect values; final reduce is
// single-block fixed-order. Agent-scope atomics handle the 8 non-coherent
// per-XCD L2s. No cross-call state: counter is re-zeroed inside the graph.

#define BATCH 1024
#define LEN   256
#define LN2f   0.6931471805599453f
#define LOG2Ef 1.4426950408889634f

__global__ void zero_counter_kernel(unsigned int* __restrict__ counter) {
    *counter = 0u;
}

__global__ __launch_bounds__(256) void bpr_fused_kernel(
    const float* __restrict__ preds,
    const int*   __restrict__ targets,
    const int*   __restrict__ mask,
    float*       __restrict__ partial,   // BATCH floats in ws
    unsigned int* __restrict__ counter,  // 1 uint in ws, zeroed by node 1
    float*       __restrict__ out)
{
    __shared__ float spos[LEN];     // positives' preds * log2e (compacted)
    __shared__ float sneg[LEN];     // negatives' preds * log2e (compacted)
    __shared__ int   wcp[4], wcn[4];
    __shared__ float wpart[4];
    __shared__ int   is_last;

    const int b    = blockIdx.x;
    const int tid  = threadIdx.x;
    const int wid  = tid >> 6;
    const int lane = tid & 63;

    const float p = preds[b * LEN + tid] * LOG2Ef;
    const int   t = targets[b * LEN + tid];
    const int   m = mask[b * LEN + tid];

    const bool ispos = (m != 0) && (t != 0);
    const bool isneg = (m != 0) && (t == 0);

    const unsigned long long bp = __ballot(ispos);
    const unsigned long long bn = __ballot(isneg);
    if (lane == 0) { wcp[wid] = __popcll(bp); wcn[wid] = __popcll(bn); }
    __syncthreads();

    int opos = 0, oneg = 0;
    for (int w = 0; w < wid; ++w) { opos += wcp[w]; oneg += wcn[w]; }
    const int np = wcp[0] + wcp[1] + wcp[2] + wcp[3];
    const int nn = wcn[0] + wcn[1] + wcn[2] + wcn[3];

    const unsigned long long below = (1ull << lane) - 1ull;
    if (ispos) spos[opos + __popcll(bp & below)] = p;
    if (isneg) sneg[oneg + __popcll(bn & below)] = p;
    __syncthreads();

    // Waves split the negative range (j uniform per wave -> LDS broadcast);
    // lanes stride the positives.
    float acc = 0.0f;
    for (int i = lane; i < np; i += 64) {
        const float yi = spos[i];
        for (int j = wid; j < nn; j += 4) {
            const float y = yi - sneg[j];
            const float e = __builtin_amdgcn_exp2f(-fabsf(y)); // v_exp_f32 -abs
            const float l = __builtin_amdgcn_logf(1.0f + e);   // v_log_f32 (log2)
            acc += fminf(y, 0.0f) - l;
        }
    }

    for (int off = 32; off > 0; off >>= 1)
        acc += __shfl_down(acc, off, 64);
    if (lane == 0) wpart[wid] = acc;
    __syncthreads();

    if (tid == 0) {
        const float bsum = wpart[0] + wpart[1] + wpart[2] + wpart[3];
        __hip_atomic_store(&partial[b], bsum, __ATOMIC_RELEASE,
                           __HIP_MEMORY_SCOPE_AGENT);
        const unsigned int old = __hip_atomic_fetch_add(
            counter, 1u, __ATOMIC_ACQ_REL, __HIP_MEMORY_SCOPE_AGENT);
        is_last = (old == (unsigned int)(gridDim.x - 1)) ? 1 : 0;
    }
    __syncthreads();

    if (is_last) {
        float racc = 0.0f;
        #pragma unroll
        for (int k = tid; k < BATCH; k += 256)
            racc += __hip_atomic_load(&partial[k], __ATOMIC_RELAXED,
                                      __HIP_MEMORY_SCOPE_AGENT);

        for (int off = 32; off > 0; off >>= 1)
            racc += __shfl_down(racc, off, 64);
        if (lane == 0) wpart[wid] = racc;
        __syncthreads();
        if (tid == 0)
            out[0] = -LN2f * (wpart[0] + wpart[1] + wpart[2] + wpart[3]);
    }
}

extern "C" void kernel_launch(void* const* d_in, const int* in_sizes, int n_in,
                              void* d_out, int out_size, void* d_ws, size_t ws_size,
                              hipStream_t stream) {
    const float* preds   = (const float*)d_in[0];
    const int*   targets = (const int*)d_in[1];
    const int*   mask    = (const int*)d_in[2];
    float* out     = (float*)d_out;
    float* partial = (float*)d_ws;                       // BATCH floats
    unsigned int* counter = (unsigned int*)((char*)d_ws + BATCH * sizeof(float));

    zero_counter_kernel<<<1, 1, 0, stream>>>(counter);
    bpr_fused_kernel<<<BATCH, 256, 0, stream>>>(preds, targets, mask,
                                                partial, counter, out);
}

// Round 6
// 13.263 us; speedup vs baseline: 10.7097x; 3.1346x over previous
//
#include <hip/hip_runtime.h>

// BPR-style pairwise ranking loss.
// loss = -sum_b sum_{i<j} log_sigmoid((p_i-p_j)(t_i-t_j)) * (t_i-t_j)^2 * m_i*m_j
// With t in {0,1}: only (valid-pos, valid-neg) pairs contribute, each unordered
// pair exactly once, with term log_sigmoid(p_pos - p_neg). So per row:
//   loss_b = -sum_{i in P} sum_{j in N} log_sigmoid(p_i - p_j)
// Base-2 form: log_sigmoid(x) = ln2 * (min(y,0) - log2(1 + 2^-|y|)), y = x*log2e.
//
// Structure notes from earlier rounds:
//  - R3/R5: agent-scope RELEASE/ACQ_REL atomics (last-block pattern) cost
//    ~40 us total (cross-XCD cache maintenance per block). NEVER again.
//  - R4: cooperative grid.sync() over 1024 blocks costs ~120 us. NEVER.
//  - R3: in-graph hipMemsetAsync node is also pathological (~40 us).
//  - R2 (two plain kernels, no atomics): 12.2 us. This round: same structure
//    but 4x fewer workgroups (256 blocks, one ROW PER WAVE, vectorized loads)
//    to test whether the ~10 us overhead scales with WG dispatch count.

#define BATCH 1024
#define LEN   256
#define RPB   4                 // rows per block = waves per block
#define NBLK  (BATCH / RPB)     // 256 blocks -> 1 per CU
#define LN2f   0.6931471805599453f
#define LOG2Ef 1.4426950408889634f

__global__ __launch_bounds__(256) void bpr_partial_kernel(
    const float* __restrict__ preds,
    const int*   __restrict__ targets,
    const int*   __restrict__ mask,
    float*       __restrict__ partial)
{
    __shared__ float spos[RPB][LEN];   // per-wave compacted positives (*log2e)
    __shared__ float sneg[RPB][LEN];   // per-wave compacted negatives (*log2e)

    const int tid  = threadIdx.x;
    const int wid  = tid >> 6;
    const int lane = tid & 63;
    const int row  = blockIdx.x * RPB + wid;
    const int base = row * LEN;

    // 4 consecutive elements per lane, fully coalesced 16B vector loads.
    const float4 p4 = *reinterpret_cast<const float4*>(preds   + base + lane * 4);
    const int4   t4 = *reinterpret_cast<const int4*>(targets + base + lane * 4);
    const int4   m4 = *reinterpret_cast<const int4*>(mask    + base + lane * 4);

    const float pv[4] = { p4.x * LOG2Ef, p4.y * LOG2Ef, p4.z * LOG2Ef, p4.w * LOG2Ef };
    const int   tv[4] = { t4.x, t4.y, t4.z, t4.w };
    const int   mv[4] = { m4.x, m4.y, m4.z, m4.w };

    // Per-wave compaction via ballot+popcount, 4 rounds (slot-major order,
    // deterministic). No cross-wave coordination needed.
    int np = 0, nn = 0;
    const unsigned long long below = (1ull << lane) - 1ull;
    #pragma unroll
    for (int s = 0; s < 4; ++s) {
        const bool ispos = (mv[s] != 0) && (tv[s] != 0);
        const bool isneg = (mv[s] != 0) && (tv[s] == 0);
        const unsigned long long bp = __ballot(ispos);
        const unsigned long long bn = __ballot(isneg);
        if (ispos) spos[wid][np + __popcll(bp & below)] = pv[s];
        if (isneg) sneg[wid][nn + __popcll(bn & below)] = pv[s];
        np += (int)__popcll(bp);
        nn += (int)__popcll(bn);
    }
    __syncthreads();   // cheap; guarantees LDS writes visible to whole wave

    // Lanes stride positives (np ~ 64 -> usually 1 iter); serial uniform
    // negative loop -> LDS broadcast reads, conflict-free.
    float acc = 0.0f;
    for (int ip = lane; ip < np; ip += 64) {
        const float yi = spos[wid][ip];
        #pragma unroll 4
        for (int jn = 0; jn < nn; ++jn) {
            const float y = yi - sneg[wid][jn];
            const float e = __builtin_amdgcn_exp2f(-fabsf(y)); // v_exp_f32 -abs
            const float l = __builtin_amdgcn_logf(1.0f + e);   // v_log_f32 (log2)
            acc += fminf(y, 0.0f) - l;
        }
    }

    // wave (64-lane) reduction; lanes with lane>=np contributed 0.
    for (int off = 32; off > 0; off >>= 1)
        acc += __shfl_down(acc, off, 64);
    if (lane == 0)
        partial[row] = acc;
}

__global__ __launch_bounds__(256) void bpr_reduce_kernel(
    const float* __restrict__ partial,
    float*       __restrict__ out)
{
    const int i = threadIdx.x;
    float acc = 0.0f;
    #pragma unroll
    for (int k = i; k < BATCH; k += 256)
        acc += partial[k];

    for (int off = 32; off > 0; off >>= 1)
        acc += __shfl_down(acc, off, 64);

    __shared__ float wpart[4];
    if ((i & 63) == 0) wpart[i >> 6] = acc;
    __syncthreads();
    if (i == 0)
        out[0] = -LN2f * (wpart[0] + wpart[1] + wpart[2] + wpart[3]);
}

extern "C" void kernel_launch(void* const* d_in, const int* in_sizes, int n_in,
                              void* d_out, int out_size, void* d_ws, size_t ws_size,
                              hipStream_t stream) {
    const float* preds   = (const float*)d_in[0];
    const int*   targets = (const int*)d_in[1];
    const int*   mask    = (const int*)d_in[2];
    float* out     = (float*)d_out;
    float* partial = (float*)d_ws;   // BATCH floats of scratch

    bpr_partial_kernel<<<NBLK, 256, 0, stream>>>(preds, targets, mask, partial);
    bpr_reduce_kernel<<<1, 256, 0, stream>>>(partial, out);
}

// Round 7
// 12.046 us; speedup vs baseline: 11.7921x; 1.1011x over previous
//
#include <hip/hip_runtime.h>

// BPR-style pairwise ranking loss.
// loss = -sum_b sum_{i<j} log_sigmoid((p_i-p_j)(t_i-t_j)) * (t_i-t_j)^2 * m_i*m_j
// With t in {0,1}: only (valid-pos, valid-neg) pairs contribute, each unordered
// pair exactly once, with term log_sigmoid(p_pos - p_neg). So per row:
//   loss_b = -sum_{i in P} sum_{j in N} log_sigmoid(p_i - p_j)
// Base-2 form: log_sigmoid(x) = ln2 * (min(y,0) - log2(1 + 2^-|y|)), y = x*log2e.
//
// Structure lessons (measured, this session):
//  - Two plain kernel nodes, no atomics = best (R2: 12.2 us; ~10 us of that
//    is a fixed graph-replay submission floor, GPU work ~2.5 us).
//  - WG count doesn't matter (R6: 4x fewer WGs -> no gain).
//  - Agent-scope release/acq_rel atomics (last-block fusion): ~40 us of
//    per-block cross-XCD L2 writeback/invalidate. NEVER.
//  - Cooperative grid.sync over 1024 blocks: ~120 us. NEVER.
//  - In-graph hipMemsetAsync node: ~40 us blit. NEVER.

#define BATCH 1024
#define LEN   256
#define LN2f   0.6931471805599453f
#define LOG2Ef 1.4426950408889634f

__global__ __launch_bounds__(256) void bpr_partial_kernel(
    const float* __restrict__ preds,
    const int*   __restrict__ targets,
    const int*   __restrict__ mask,
    float*       __restrict__ partial)
{
    __shared__ float spos[LEN];     // positives' preds * log2e (compacted)
    __shared__ float sneg[LEN];     // negatives' preds * log2e (compacted)
    __shared__ int   wcp[4], wcn[4];
    __shared__ float wpart[4];

    const int b    = blockIdx.x;
    const int tid  = threadIdx.x;
    const int wid  = tid >> 6;
    const int lane = tid & 63;

    const float p = preds[b * LEN + tid] * LOG2Ef;
    const int   t = targets[b * LEN + tid];
    const int   m = mask[b * LEN + tid];

    const bool ispos = (m != 0) && (t != 0);
    const bool isneg = (m != 0) && (t == 0);

    const unsigned long long bp = __ballot(ispos);
    const unsigned long long bn = __ballot(isneg);
    if (lane == 0) { wcp[wid] = __popcll(bp); wcn[wid] = __popcll(bn); }
    __syncthreads();

    int opos = 0, oneg = 0;
    for (int w = 0; w < wid; ++w) { opos += wcp[w]; oneg += wcn[w]; }
    const int np = wcp[0] + wcp[1] + wcp[2] + wcp[3];
    const int nn = wcn[0] + wcn[1] + wcn[2] + wcn[3];

    const unsigned long long below = (1ull << lane) - 1ull;
    if (ispos) spos[opos + __popcll(bp & below)] = p;
    if (isneg) sneg[oneg + __popcll(bn & below)] = p;
    __syncthreads();

    // Waves split the negative range (j uniform per wave -> LDS broadcast);
    // lanes stride the positives. Critical path: ~16 inner iterations.
    float acc = 0.0f;
    for (int i = lane; i < np; i += 64) {
        const float yi = spos[i];
        #pragma unroll 4
        for (int j = wid; j < nn; j += 4) {
            const float y = yi - sneg[j];
            const float e = __builtin_amdgcn_exp2f(-fabsf(y)); // v_exp_f32 -abs
            const float l = __builtin_amdgcn_logf(1.0f + e);   // v_log_f32 (log2)
            acc += fminf(y, 0.0f) - l;
        }
    }

    for (int off = 32; off > 0; off >>= 1)
        acc += __shfl_down(acc, off, 64);
    if (lane == 0) wpart[wid] = acc;
    __syncthreads();
    if (tid == 0)
        partial[b] = wpart[0] + wpart[1] + wpart[2] + wpart[3];
}

__global__ __launch_bounds__(256) void bpr_reduce_kernel(
    const float* __restrict__ partial,
    float*       __restrict__ out)
{
    const int i = threadIdx.x;
    float acc = 0.0f;
    #pragma unroll
    for (int k = i; k < BATCH; k += 256)
        acc += partial[k];

    for (int off = 32; off > 0; off >>= 1)
        acc += __shfl_down(acc, off, 64);

    __shared__ float wpart[4];
    if ((i & 63) == 0) wpart[i >> 6] = acc;
    __syncthreads();
    if (i == 0)
        out[0] = -LN2f * (wpart[0] + wpart[1] + wpart[2] + wpart[3]);
}

extern "C" void kernel_launch(void* const* d_in, const int* in_sizes, int n_in,
                              void* d_out, int out_size, void* d_ws, size_t ws_size,
                              hipStream_t stream) {
    const float* preds   = (const float*)d_in[0];
    const int*   targets = (const int*)d_in[1];
    const int*   mask    = (const int*)d_in[2];
    float* out     = (float*)d_out;
    float* partial = (float*)d_ws;   // BATCH floats of scratch

    bpr_partial_kernel<<<BATCH, 256, 0, stream>>>(preds, targets, mask, partial);
    bpr_reduce_kernel<<<1, 256, 0, stream>>>(partial, out);
}